// Round 1
// baseline (2513.136 us; speedup 1.0000x reference)
//
#include <hip/hip_runtime.h>

#define NPLANE 16384
#define EPSF 1e-5f
#define NEGF -1e30f

// d_ws float offsets (total 163840 floats = 640 KB)
#define WS_PWT 0          // 4 x 128x128: pwT[i][c][o] = pw_w[i][o][c]
#define WS_FCT 65536      // fcT[c][o] = fc_w[o][c]
#define WS_WOT 81920      // woT[jg][f] = Wo[f][jg]
#define WS_WQT 98304      // wqT[l][jg] = Wq[jg][l]
#define WS_WKT 114688
#define WS_WVT 131072
#define WS_PE  147456     // PE[d][pos], fp64-accurate

__device__ __forceinline__ unsigned short f2bf(float x) {
  unsigned int u = __float_as_uint(x);
  u += 0x7fffu + ((u >> 16) & 1u);
  return (unsigned short)(u >> 16);
}

__global__ __launch_bounds__(128) void prep_kernel(
    const float* __restrict__ pw_w, const float* __restrict__ fc_w,
    const float* __restrict__ Wo, const float* __restrict__ Wq,
    const float* __restrict__ Wk, const float* __restrict__ Wv,
    float* __restrict__ ws) {
  int job = blockIdx.x, r = blockIdx.y, c = threadIdx.x;
  if (job < 4)       ws[WS_PWT + job * NPLANE + r * 128 + c] = pw_w[job * NPLANE + c * 128 + r];
  else if (job == 4) ws[WS_FCT + r * 128 + c] = fc_w[c * 128 + r];
  else if (job == 5) ws[WS_WOT + r * 128 + c] = Wo[c * 128 + r];
  else if (job == 6) ws[WS_WQT + r * 128 + c] = Wq[c * 128 + r];
  else if (job == 7) ws[WS_WKT + r * 128 + c] = Wk[c * 128 + r];
  else if (job == 8) ws[WS_WVT + r * 128 + c] = Wv[c * 128 + r];
  else {
    int d = r, pos = c;
    double freq, phase;
    if ((d & 1) == 0) { freq = pow(10000.0, -(double)d / 128.0); phase = 0.0; }
    else { freq = -pow(10000.0, (1.0 - (double)d) / 128.0); phase = 1.5707963267948966; }
    ws[WS_PE + d * 128 + pos] = (float)sin((double)pos * freq + phase);
  }
}

// Plane-wide LayerNorm over res[] regs -> write normalized*w+b into P1[o*128+l].
__device__ __forceinline__ void ln_write(float* __restrict__ P1, float* red,
    const float* resv, const float* __restrict__ wg, const float* __restrict__ bg,
    int t, int l, int obase) {
  float s = 0.f, s2 = 0.f;
#pragma unroll
  for (int i = 0; i < 32; i++) { float v = resv[i]; s += v; s2 += v * v; }
#pragma unroll
  for (int off = 32; off > 0; off >>= 1) {
    s += __shfl_down(s, off, 64);
    s2 += __shfl_down(s2, off, 64);
  }
  if ((t & 63) == 0) { red[(t >> 6) * 2] = s; red[(t >> 6) * 2 + 1] = s2; }
  __syncthreads();
  float S = 0.f, S2 = 0.f;
#pragma unroll
  for (int i = 0; i < 8; i++) { S += red[2 * i]; S2 += red[2 * i + 1]; }
  float mu = S * (1.0f / 16384.0f);
  float var = S2 * (1.0f / 16384.0f) - mu * mu;
  float inv = rsqrtf(var + EPSF);
#pragma unroll
  for (int i = 0; i < 32; i++) {
    int o = obase + i;
    P1[o * 128 + l] = (resv[i] - mu) * inv * wg[o * 128 + l] + bg[o * 128 + l];
  }
  __syncthreads();
}

__global__ __launch_bounds__(512, 2) void enc_kernel(
    const float* __restrict__ x, const int* __restrict__ mask,
    const float* __restrict__ dw_w, const float* __restrict__ dw_b,
    const float* __restrict__ pw_b,
    const float* __restrict__ normb_w, const float* __restrict__ normb_b,
    const float* __restrict__ norms_w, const float* __restrict__ norms_b,
    const float* __restrict__ norme_w, const float* __restrict__ norme_b,
    const float* __restrict__ bq, const float* __restrict__ bk,
    const float* __restrict__ bv, const float* __restrict__ bo,
    const float* __restrict__ fc_b, const float* __restrict__ ws,
    float* __restrict__ out) {
  __shared__ float P1[128 * 128];          // stride 128: cur plane / kT,vT
  __shared__ float P2[128 * 129];          // stride 129: dw scratch / curT
  __shared__ unsigned int E2[128 * 32];    // attention-out rows, bf16 pairs
  __shared__ float mask_s[128];
  __shared__ float red[16];

  const int t = threadIdx.x;
  const int b = blockIdx.x;
  const int l = t & 127;                 // owned column (length / feature axis)
  const int obase = (t >> 7) * 32;       // owned 32 channel rows
  const int obase_s = __builtin_amdgcn_readfirstlane(obase);

  if (t < 128) mask_s[t] = (float)mask[b * 128 + t];

  float res[32];  // residual (pre-LN) values this thread owns
  {
    const float* xb = x + (size_t)b * NPLANE;
    const float* pe = ws + WS_PE;
#pragma unroll
    for (int i = 0; i < 32; i++) {
      int o = obase + i;
      res[i] = xb[o * 128 + l] + pe[o * 128 + l];
    }
  }
  ln_write(P1, red, res, normb_w, normb_b, t, l, obase);

  // ---------------- 4x separable conv blocks ----------------
#pragma unroll 1
  for (int layer = 0; layer < 4; layer++) {
    // depthwise conv7 along l: P1 -> P2
    const float* dww = dw_w + layer * 128 * 7;
    const float* dwb = dw_b + layer * 128;
#pragma unroll
    for (int i = 0; i < 32; i++) {
      int o = obase_s + i;
      float acc = dwb[o];
#pragma unroll
      for (int j = 0; j < 7; j++) {
        int p = l + j - 3;
        float xv = (p >= 0 && p < 128) ? P1[o * 128 + p] : 0.f;
        acc += xv * dww[o * 7 + j];
      }
      P2[o * 129 + l] = acc;
    }
    __syncthreads();
    // pointwise 128x128 (pwT scalar weights, P2 row reads)
    const float* pwT = ws + WS_PWT + layer * NPLANE;
    float acc[32];
#pragma unroll
    for (int i = 0; i < 32; i++) acc[i] = 0.f;
    for (int c = 0; c < 128; c++) {
      float a = P2[c * 129 + l];
      const float* wrow = pwT + c * 128 + obase_s;
#pragma unroll
      for (int i = 0; i < 32; i++) acc[i] += wrow[i] * a;
    }
    const float* pwb = pw_b + layer * 128;
#pragma unroll
    for (int i = 0; i < 32; i++) {
      float h = acc[i] + pwb[obase_s + i];
      res[i] += fmaxf(h, 0.f);
    }
    ln_write(P1, red, res, norms_w + layer * NPLANE, norms_b + layer * NPLANE, t, l, obase);
  }

  // ---------------- MHA (seq = channel axis, feat = l axis) ----------------
  // transpose P1 -> P2: curT[li][c] = cur[c][li]
#pragma unroll
  for (int i = 0; i < 32; i++) {
    int o = obase + i;
    P2[l * 129 + o] = P1[o * 128 + l];
  }
  __syncthreads();

  const int wvid = t >> 6;
  const int lane = t & 63;
  const int hh_s = __builtin_amdgcn_readfirstlane(wvid >> 2);       // head-in-pair
  const int rrow = ((wvid & 3) << 5) + (lane >> 1);                 // query row
  const int ckhalf = lane & 1;                                      // ck split
  const int jb_s = __builtin_amdgcn_readfirstlane((t >> 7) * 16);   // kv j-slice

  float proj[32];
#pragma unroll
  for (int i = 0; i < 32; i++) proj[i] = 0.f;

#pragma unroll 1
  for (int pass = 0; pass < 2; pass++) {     // heads {2p, 2p+1}
    // k,v for both heads of the pair -> P1 rows [jl][ck] (k: 0..63, v: 64..127)
    {
      float kacc[16], vacc[16];
#pragma unroll
      for (int jj = 0; jj < 16; jj++) {
        kacc[jj] = bk[pass * 64 + jb_s + jj];
        vacc[jj] = bv[pass * 64 + jb_s + jj];
      }
      for (int li = 0; li < 128; li++) {
        float a = P2[li * 129 + l];
        const float* wk = ws + WS_WKT + li * 128 + pass * 64 + jb_s;
        const float* wv = ws + WS_WVT + li * 128 + pass * 64 + jb_s;
#pragma unroll
        for (int jj = 0; jj < 16; jj++) {
          kacc[jj] += wk[jj] * a;
          vacc[jj] += wv[jj] * a;
        }
      }
#pragma unroll
      for (int jj = 0; jj < 16; jj++) {
        P1[(jb_s + jj) * 128 + l] = kacc[jj];
        P1[(64 + jb_s + jj) * 128 + l] = vacc[jj];
      }
    }
    // this thread's q row (head hh of the pair), kept in regs
    float q[32];
#pragma unroll
    for (int j = 0; j < 32; j++) q[j] = bq[pass * 64 + hh_s * 32 + j];
    for (int li = 0; li < 128; li++) {
      float a = P2[li * 129 + rrow];
      const float* wq = ws + WS_WQT + li * 128 + pass * 64 + hh_s * 32;
#pragma unroll
      for (int j = 0; j < 32; j++) q[j] += wq[j] * a;
    }
    __syncthreads();

    // flash (online softmax) over this lane's 64 ck values
    float mrun = -INFINITY, lsum = 0.f;
    float oacc[32];
#pragma unroll
    for (int j = 0; j < 32; j++) oacc[j] = 0.f;
    const int kbase = hh_s * 32 * 128;
    const int vbase = (64 + hh_s * 32) * 128;
    for (int s = 0; s < 64; s++) {
      int ck = (ckhalf << 6) + s;
      float sc = 0.f;
#pragma unroll
      for (int j = 0; j < 32; j++) sc += q[j] * P1[kbase + j * 128 + ck];
      sc *= 0.17677669529663687f;  // 1/sqrt(32)
      float m = mask_s[ck];
      sc = (m > 0.5f) ? NEGF : sc;
      float mn = fmaxf(mrun, sc);
      float al = __expf(mrun - mn);
      float p = __expf(sc - mn);
      lsum = lsum * al + p;
#pragma unroll
      for (int j = 0; j < 32; j++)
        oacc[j] = oacc[j] * al + p * P1[vbase + j * 128 + ck];
      mrun = mn;
    }
    // merge the two ck-halves (lane pairs) and normalize
    float m_o = __shfl_xor(mrun, 1, 64);
    float mm = fmaxf(mrun, m_o);
    float f = __expf(mrun - mm);
    float lsc = lsum * f;
    float ltot = lsc + __shfl_xor(lsc, 1, 64);
    float linv = 1.0f / ltot;
#pragma unroll
    for (int j = 0; j < 32; j++) {
      float a = oacc[j] * f;
      a += __shfl_xor(a, 1, 64);
      oacc[j] = a * linv;
    }
    if (ckhalf == 0) {
#pragma unroll
      for (int j = 0; j < 32; j += 2) {
        unsigned int u = (unsigned int)f2bf(oacc[j]) | ((unsigned int)f2bf(oacc[j + 1]) << 16);
        E2[rrow * 32 + hh_s * 16 + (j >> 1)] = u;
      }
    }
    __syncthreads();

    // accumulate Wo projection for this pass's 64 jg columns into proj[] regs
#pragma unroll 1
    for (int half = 0; half < 2; half++) {
      float wreg[32];
#pragma unroll
      for (int jj = 0; jj < 32; jj++)
        wreg[jj] = ws[WS_WOT + (pass * 64 + half * 32 + jj) * 128 + l];
#pragma unroll 1
      for (int ci = 0; ci < 32; ci++) {
        int c = obase_s + ci;
        float accp = 0.f;
#pragma unroll
        for (int jp = 0; jp < 16; jp++) {
          unsigned int u = E2[c * 32 + half * 16 + jp];
          float f0 = __uint_as_float(u << 16);
          float f1 = __uint_as_float(u & 0xffff0000u);
          accp += f0 * wreg[jp * 2] + f1 * wreg[jp * 2 + 1];
        }
        proj[ci] += accp;
      }
    }
    __syncthreads();
  }

  // att + bo + residual, final LN
  {
    float bov = bo[l];
#pragma unroll
    for (int i = 0; i < 32; i++) res[i] += proj[i] + bov;
  }
  ln_write(P1, red, res, norme_w, norme_b, t, l, obase);

  // ---------------- FC + relu + residual -> out ----------------
  {
    const float* fcT = ws + WS_FCT;
    float acc[32];
#pragma unroll
    for (int i = 0; i < 32; i++) acc[i] = 0.f;
    for (int c = 0; c < 128; c++) {
      float a = P1[c * 128 + l];
      const float* wrow = fcT + c * 128 + obase_s;
#pragma unroll
      for (int i = 0; i < 32; i++) acc[i] += wrow[i] * a;
    }
    float* outb = out + (size_t)b * NPLANE;
#pragma unroll
    for (int i = 0; i < 32; i++) {
      float h = acc[i] + fc_b[obase_s + i];
      outb[(obase + i) * 128 + l] = fmaxf(h, 0.f) + res[i];
    }
  }
}

extern "C" void kernel_launch(void* const* d_in, const int* in_sizes, int n_in,
                              void* d_out, int out_size, void* d_ws, size_t ws_size,
                              hipStream_t stream) {
  const float* x       = (const float*)d_in[0];
  const int*   mask    = (const int*)d_in[1];
  const float* dw_w    = (const float*)d_in[2];
  const float* dw_b    = (const float*)d_in[3];
  const float* pw_w    = (const float*)d_in[4];
  const float* pw_b    = (const float*)d_in[5];
  const float* normb_w = (const float*)d_in[6];
  const float* normb_b = (const float*)d_in[7];
  const float* norms_w = (const float*)d_in[8];
  const float* norms_b = (const float*)d_in[9];
  const float* norme_w = (const float*)d_in[10];
  const float* norme_b = (const float*)d_in[11];
  const float* Wq      = (const float*)d_in[12];
  const float* bq      = (const float*)d_in[13];
  const float* Wk      = (const float*)d_in[14];
  const float* bk      = (const float*)d_in[15];
  const float* Wv      = (const float*)d_in[16];
  const float* bv      = (const float*)d_in[17];
  const float* Wo      = (const float*)d_in[18];
  const float* bo      = (const float*)d_in[19];
  const float* fc_w    = (const float*)d_in[20];
  const float* fc_b    = (const float*)d_in[21];
  float* out = (float*)d_out;
  float* ws  = (float*)d_ws;
  int B = in_sizes[0] / NPLANE;

  prep_kernel<<<dim3(10, 128), dim3(128), 0, stream>>>(pw_w, fc_w, Wo, Wq, Wk, Wv, ws);
  enc_kernel<<<dim3(B), dim3(512), 0, stream>>>(
      x, mask, dw_w, dw_b, pw_b, normb_w, normb_b, norms_w, norms_b,
      norme_w, norme_b, bq, bk, bv, bo, fc_b, ws, out);
}

// Round 2
// 610.344 us; speedup vs baseline: 4.1176x; 4.1176x over previous
//
#include <hip/hip_runtime.h>

#define NEGF -1e30f
#define EPSF 1e-5f

typedef __attribute__((ext_vector_type(8))) short bf16x8;
typedef __attribute__((ext_vector_type(4))) float f32x4;

// ws layout, ushort units
#define WSU_PW 0            // 4 x 128x128 bf16, natural [o][c]
#define WSU_FC 65536        // [o][c]
#define WSU_WO 81920        // [f][j]
#define WSU_WQ 98304        // [j][l]
#define WSU_WK 114688
#define WSU_WV 131072
#define WSU_END 147456      // then PE as float[16384]

__device__ __forceinline__ unsigned short f2bf(float x) {
  unsigned int u = __float_as_uint(x);
  u += 0x7fffu + ((u >> 16) & 1u);
  return (unsigned short)(u >> 16);
}
__device__ __forceinline__ float bf2f(unsigned short u) {
  return __uint_as_float(((unsigned int)u) << 16);
}
__device__ __forceinline__ f32x4 mfma16(bf16x8 a, bf16x8 b, f32x4 c) {
  return __builtin_amdgcn_mfma_f32_16x16x32_bf16(a, b, c, 0, 0, 0);
}

__global__ __launch_bounds__(128) void prep_kernel(
    const float* __restrict__ pw_w, const float* __restrict__ fc_w,
    const float* __restrict__ Wo, const float* __restrict__ Wq,
    const float* __restrict__ Wk, const float* __restrict__ Wv,
    unsigned short* __restrict__ wsu) {
  int job = blockIdx.x, r = blockIdx.y, c = threadIdx.x;
  int idx = r * 128 + c;
  if (job < 4)       wsu[WSU_PW + job * 16384 + idx] = f2bf(pw_w[job * 16384 + idx]);
  else if (job == 4) wsu[WSU_FC + idx] = f2bf(fc_w[idx]);
  else if (job == 5) wsu[WSU_WO + idx] = f2bf(Wo[idx]);
  else if (job == 6) wsu[WSU_WQ + idx] = f2bf(Wq[idx]);
  else if (job == 7) wsu[WSU_WK + idx] = f2bf(Wk[idx]);
  else if (job == 8) wsu[WSU_WV + idx] = f2bf(Wv[idx]);
  else {
    float* pe = (float*)(wsu + WSU_END);
    int d = r, pos = c;
    double freq, phase;
    if ((d & 1) == 0) { freq = pow(10000.0, -(double)d / 128.0); phase = 0.0; }
    else { freq = -pow(10000.0, (1.0 - (double)d) / 128.0); phase = 1.5707963267948966; }
    pe[d * 128 + pos] = (float)sin((double)pos * freq + phase);
  }
}

// plane LN stats over 512 threads x 32 regs
__device__ __forceinline__ void ln_stats(const float* resv, float* red, int t,
                                         float& mu, float& inv) {
  float s = 0.f, s2 = 0.f;
#pragma unroll
  for (int i = 0; i < 32; i++) { float v = resv[i]; s += v; s2 += v * v; }
#pragma unroll
  for (int off = 32; off > 0; off >>= 1) {
    s += __shfl_down(s, off, 64);
    s2 += __shfl_down(s2, off, 64);
  }
  if ((t & 63) == 0) { red[(t >> 6) * 2] = s; red[(t >> 6) * 2 + 1] = s2; }
  __syncthreads();
  float S = 0.f, S2 = 0.f;
#pragma unroll
  for (int i = 0; i < 8; i++) { S += red[2 * i]; S2 += red[2 * i + 1]; }
  mu = S * (1.0f / 16384.0f);
  float var = S2 * (1.0f / 16384.0f) - mu * mu;
  inv = rsqrtf(var + EPSF);
}

__global__ __launch_bounds__(512, 2) void enc_kernel(
    const float* __restrict__ x, const int* __restrict__ mask,
    const float* __restrict__ dw_w, const float* __restrict__ dw_b,
    const float* __restrict__ pw_b,
    const float* __restrict__ normb_w, const float* __restrict__ normb_b,
    const float* __restrict__ norms_w, const float* __restrict__ norms_b,
    const float* __restrict__ norme_w, const float* __restrict__ norme_b,
    const float* __restrict__ bq, const float* __restrict__ bk,
    const float* __restrict__ bv, const float* __restrict__ bo,
    const float* __restrict__ fc_b, const unsigned short* __restrict__ wsu,
    const float* __restrict__ pe, float* __restrict__ out) {
  __shared__ __align__(16) float S[128 * 130];            // fp32 matmul-out scratch (+ MHA union)
  __shared__ __align__(16) unsigned short Xn_raw[128 * 136 + 16];
  __shared__ __align__(16) unsigned short HT[128 * 136];  // h^T / ATT / X^T
  __shared__ float mask_s[128];
  __shared__ float red[16];
  unsigned short* Xn = Xn_raw + 8;
  // MHA union inside S (64,000 shorts <= 66,560 floats*2)
  unsigned short* Pn  = (unsigned short*)S;   // 128*136
  unsigned short* Qh  = Pn + 128 * 136;       // 128*40
  unsigned short* Kh  = Qh + 128 * 40;        // 128*40
  unsigned short* VTh = Kh + 128 * 40;        // 32*136

  const int t = threadIdx.x;
  const int b = blockIdx.x;
  const int lane = t & 63;
  const int r16 = lane & 15;
  const int quad = lane >> 4;
  const int m0 = __builtin_amdgcn_readfirstlane((t >> 6) << 4);   // wave m-tile base
  const int l = t & 127;                                          // owned column
  const int obase = __builtin_amdgcn_readfirstlane((t >> 7) << 5);
  const int dw_o = t & 127;                                       // depthwise row
  const int dw_seg = __builtin_amdgcn_readfirstlane(t >> 7);      // depthwise l-segment

  if (t < 128) mask_s[t] = (float)mask[b * 128 + t];

  float res[32];
  {
    const float* xb = x + (size_t)b * 16384;
#pragma unroll
    for (int i = 0; i < 32; i++) {
      int o = obase + i;
      res[i] = xb[o * 128 + l] + pe[o * 128 + l];
    }
  }
  {
    float mu, inv;
    ln_stats(res, red, t, mu, inv);
#pragma unroll
    for (int i = 0; i < 32; i++) {
      int o = obase + i;
      Xn[o * 136 + l] = f2bf((res[i] - mu) * inv * normb_w[o * 128 + l] + normb_b[o * 128 + l]);
    }
    __syncthreads();
  }

  // ================= 4x separable conv blocks =================
#pragma unroll 1
  for (int layer = 0; layer < 4; layer++) {
    // depthwise conv7: Xn -> HT (transposed h^T[l][c])
    {
      const float* dwp = dw_w + layer * 896 + dw_o * 7;
      float wreg[7];
#pragma unroll
      for (int j = 0; j < 7; j++) wreg[j] = dwp[j];
      float bias = dw_b[layer * 128 + dw_o];
      const unsigned short* xrow = Xn + dw_o * 136 + dw_seg * 32 - 8;
      float f[48];
#pragma unroll
      for (int i6 = 0; i6 < 6; i6++) {
        bf16x8 v = *(const bf16x8*)(xrow + 8 * i6);
#pragma unroll
        for (int j = 0; j < 8; j++) f[i6 * 8 + j] = bf2f((unsigned short)v[j]);
      }
      if (dw_seg == 0) {
#pragma unroll
        for (int i = 0; i < 8; i++) f[i] = 0.f;
      }
      if (dw_seg == 3) {
#pragma unroll
        for (int i = 40; i < 48; i++) f[i] = 0.f;
      }
      float accv[32];
#pragma unroll
      for (int c = 0; c < 32; c++) {
        float a = bias;
#pragma unroll
        for (int j = 0; j < 7; j++) a += f[c + 5 + j] * wreg[j];  // idx = c + j + 5
        accv[c] = a;
      }
#pragma unroll
      for (int c = 0; c < 32; c++) HT[(dw_seg * 32 + c) * 136 + dw_o] = f2bf(accv[c]);
    }
    __syncthreads();
    // pointwise: D[o][l] = sum_c pw[o][c] * hT[l][c]
    {
      const unsigned short* pwp = wsu + WSU_PW + (layer << 14) + (m0 + r16) * 128 + quad * 8;
      bf16x8 a0 = *(const bf16x8*)(pwp);
      bf16x8 a1 = *(const bf16x8*)(pwp + 32);
      bf16x8 a2 = *(const bf16x8*)(pwp + 64);
      bf16x8 a3 = *(const bf16x8*)(pwp + 96);
#pragma unroll
      for (int n = 0; n < 8; n++) {
        const unsigned short* hb = HT + (16 * n + r16) * 136 + quad * 8;
        f32x4 c = {0.f, 0.f, 0.f, 0.f};
        c = mfma16(a0, *(const bf16x8*)(hb), c);
        c = mfma16(a1, *(const bf16x8*)(hb + 32), c);
        c = mfma16(a2, *(const bf16x8*)(hb + 64), c);
        c = mfma16(a3, *(const bf16x8*)(hb + 96), c);
        float* sp = S + (m0 + quad * 4) * 130 + 16 * n + r16;
        sp[0] = c[0]; sp[130] = c[1]; sp[260] = c[2]; sp[390] = c[3];
      }
    }
    __syncthreads();
    // res += relu(S + bias); LN -> Xn
    {
#pragma unroll
      for (int i = 0; i < 32; i++)
        res[i] += fmaxf(S[(obase + i) * 130 + l] + pw_b[layer * 128 + obase + i], 0.f);
      float mu, inv;
      ln_stats(res, red, t, mu, inv);
      const float* wg = norms_w + layer * 16384;
      const float* bg = norms_b + layer * 16384;
#pragma unroll
      for (int i = 0; i < 32; i++) {
        int o = obase + i;
        Xn[o * 136 + l] = f2bf((res[i] - mu) * inv * wg[o * 128 + l] + bg[o * 128 + l]);
      }
      __syncthreads();
    }
  }

  // ================= MHA (seq = channels, DK=32 per head) =================
#pragma unroll 1
  for (int h = 0; h < 4; h++) {
    __syncthreads();  // prior head's Pn/VTh readers done before overwriting S-union
    // ---- Q,K,V for this head: D[c][j'] = sum_l Xn[c][l] * W[j][l]
    {
      const unsigned short* xp = Xn + (m0 + r16) * 136 + quad * 8;
      bf16x8 x0 = *(const bf16x8*)(xp);
      bf16x8 x1 = *(const bf16x8*)(xp + 32);
      bf16x8 x2 = *(const bf16x8*)(xp + 64);
      bf16x8 x3 = *(const bf16x8*)(xp + 96);
#pragma unroll
      for (int n = 0; n < 2; n++) {
        const int jrow = 32 * h + 16 * n + r16;
        // Q (scale folded)
        {
          const unsigned short* wp = wsu + WSU_WQ + jrow * 128 + quad * 8;
          f32x4 c = {0.f, 0.f, 0.f, 0.f};
          c = mfma16(x0, *(const bf16x8*)(wp), c);
          c = mfma16(x1, *(const bf16x8*)(wp + 32), c);
          c = mfma16(x2, *(const bf16x8*)(wp + 64), c);
          c = mfma16(x3, *(const bf16x8*)(wp + 96), c);
          float bb = bq[jrow];
#pragma unroll
          for (int r = 0; r < 4; r++)
            Qh[(m0 + quad * 4 + r) * 40 + 16 * n + r16] =
                f2bf((c[r] + bb) * 0.17677669529663687f);
        }
        // K
        {
          const unsigned short* wp = wsu + WSU_WK + jrow * 128 + quad * 8;
          f32x4 c = {0.f, 0.f, 0.f, 0.f};
          c = mfma16(x0, *(const bf16x8*)(wp), c);
          c = mfma16(x1, *(const bf16x8*)(wp + 32), c);
          c = mfma16(x2, *(const bf16x8*)(wp + 64), c);
          c = mfma16(x3, *(const bf16x8*)(wp + 96), c);
          float bb = bk[jrow];
#pragma unroll
          for (int r = 0; r < 4; r++)
            Kh[(m0 + quad * 4 + r) * 40 + 16 * n + r16] = f2bf(c[r] + bb);
        }
        // V -> VTh[j'][ck] (transposed, packed pairs)
        {
          const unsigned short* wp = wsu + WSU_WV + jrow * 128 + quad * 8;
          f32x4 c = {0.f, 0.f, 0.f, 0.f};
          c = mfma16(x0, *(const bf16x8*)(wp), c);
          c = mfma16(x1, *(const bf16x8*)(wp + 32), c);
          c = mfma16(x2, *(const bf16x8*)(wp + 64), c);
          c = mfma16(x3, *(const bf16x8*)(wp + 96), c);
          float bb = bv[jrow];
          unsigned int lo = (unsigned int)f2bf(c[0] + bb) | ((unsigned int)f2bf(c[1] + bb) << 16);
          unsigned int hi = (unsigned int)f2bf(c[2] + bb) | ((unsigned int)f2bf(c[3] + bb) << 16);
          unsigned short* vp = VTh + (16 * n + r16) * 136 + m0 + quad * 4;
          *(unsigned int*)(vp) = lo;
          *(unsigned int*)(vp + 2) = hi;
        }
      }
    }
    __syncthreads();
    // ---- scores + in-register masked softmax -> Pn (unnormalized bf16)
    float linv[4];
    {
      bf16x8 aq = *(const bf16x8*)(Qh + (m0 + r16) * 40 + quad * 8);
      f32x4 sc[8];
#pragma unroll
      for (int n = 0; n < 8; n++) {
        f32x4 z = {0.f, 0.f, 0.f, 0.f};
        sc[n] = mfma16(aq, *(const bf16x8*)(Kh + (16 * n + r16) * 40 + quad * 8), z);
      }
      float mv[8];
#pragma unroll
      for (int n = 0; n < 8; n++) mv[n] = mask_s[16 * n + r16];
#pragma unroll
      for (int r = 0; r < 4; r++) {
        float sv[8];
#pragma unroll
        for (int n = 0; n < 8; n++) sv[n] = (mv[n] > 0.5f) ? NEGF : sc[n][r];
        float mx = sv[0];
#pragma unroll
        for (int n = 1; n < 8; n++) mx = fmaxf(mx, sv[n]);
        mx = fmaxf(mx, __shfl_xor(mx, 1, 64));
        mx = fmaxf(mx, __shfl_xor(mx, 2, 64));
        mx = fmaxf(mx, __shfl_xor(mx, 4, 64));
        mx = fmaxf(mx, __shfl_xor(mx, 8, 64));
        float sum = 0.f;
#pragma unroll
        for (int n = 0; n < 8; n++) { float p = __expf(sv[n] - mx); sv[n] = p; sum += p; }
        sum += __shfl_xor(sum, 1, 64);
        sum += __shfl_xor(sum, 2, 64);
        sum += __shfl_xor(sum, 4, 64);
        sum += __shfl_xor(sum, 8, 64);
        linv[r] = 1.0f / sum;
        unsigned short* pp = Pn + (m0 + quad * 4 + r) * 136 + r16;
#pragma unroll
        for (int n = 0; n < 8; n++) pp[16 * n] = f2bf(sv[n]);
      }
    }
    // ---- PV: D[cq][j'] = sum_ck P[cq][ck] * VTh[j'][ck]; *linv; -> ATT(HT)
    {
      const unsigned short* pq = Pn + (m0 + r16) * 136 + quad * 8;
      bf16x8 p0 = *(const bf16x8*)(pq);
      bf16x8 p1 = *(const bf16x8*)(pq + 32);
      bf16x8 p2 = *(const bf16x8*)(pq + 64);
      bf16x8 p3 = *(const bf16x8*)(pq + 96);
#pragma unroll
      for (int n = 0; n < 2; n++) {
        const unsigned short* vb = VTh + (16 * n + r16) * 136 + quad * 8;
        f32x4 c = {0.f, 0.f, 0.f, 0.f};
        c = mfma16(p0, *(const bf16x8*)(vb), c);
        c = mfma16(p1, *(const bf16x8*)(vb + 32), c);
        c = mfma16(p2, *(const bf16x8*)(vb + 64), c);
        c = mfma16(p3, *(const bf16x8*)(vb + 96), c);
#pragma unroll
        for (int r = 0; r < 4; r++)
          HT[(m0 + quad * 4 + r) * 136 + 32 * h + 16 * n + r16] = f2bf(c[r] * linv[r]);
      }
    }
  }
  __syncthreads();  // all PV reads of S-union done before Wo writes S

  // ---- Wo: D[c][f] = sum_j ATT[c][j] * Wo[f][j] -> S
  {
    const unsigned short* ap = HT + (m0 + r16) * 136 + quad * 8;
    bf16x8 a0 = *(const bf16x8*)(ap);
    bf16x8 a1 = *(const bf16x8*)(ap + 32);
    bf16x8 a2 = *(const bf16x8*)(ap + 64);
    bf16x8 a3 = *(const bf16x8*)(ap + 96);
#pragma unroll
    for (int n = 0; n < 8; n++) {
      const unsigned short* wp = wsu + WSU_WO + (16 * n + r16) * 128 + quad * 8;
      f32x4 c = {0.f, 0.f, 0.f, 0.f};
      c = mfma16(a0, *(const bf16x8*)(wp), c);
      c = mfma16(a1, *(const bf16x8*)(wp + 32), c);
      c = mfma16(a2, *(const bf16x8*)(wp + 64), c);
      c = mfma16(a3, *(const bf16x8*)(wp + 96), c);
      float* sp = S + (m0 + quad * 4) * 130 + 16 * n + r16;
      sp[0] = c[0]; sp[130] = c[1]; sp[260] = c[2]; sp[390] = c[3];
    }
  }
  __syncthreads();
  // res += att + bo; final LN -> X^T into HT
  {
    float bol = bo[l];
#pragma unroll
    for (int i = 0; i < 32; i++) res[i] += S[(obase + i) * 130 + l] + bol;
    float mu, inv;
    ln_stats(res, red, t, mu, inv);
#pragma unroll
    for (int i = 0; i < 32; i += 2) {
      int o = obase + i;
      float v0 = (res[i] - mu) * inv * norme_w[o * 128 + l] + norme_b[o * 128 + l];
      float v1 = (res[i + 1] - mu) * inv * norme_w[(o + 1) * 128 + l] + norme_b[(o + 1) * 128 + l];
      *(unsigned int*)(HT + l * 136 + o) =
          (unsigned int)f2bf(v0) | ((unsigned int)f2bf(v1) << 16);
    }
    __syncthreads();
  }
  // ---- FC: D[o][l] = sum_c fc[o][c] * XT[l][c] -> S
  {
    const unsigned short* fp = wsu + WSU_FC + (m0 + r16) * 128 + quad * 8;
    bf16x8 a0 = *(const bf16x8*)(fp);
    bf16x8 a1 = *(const bf16x8*)(fp + 32);
    bf16x8 a2 = *(const bf16x8*)(fp + 64);
    bf16x8 a3 = *(const bf16x8*)(fp + 96);
#pragma unroll
    for (int n = 0; n < 8; n++) {
      const unsigned short* hb = HT + (16 * n + r16) * 136 + quad * 8;
      f32x4 c = {0.f, 0.f, 0.f, 0.f};
      c = mfma16(a0, *(const bf16x8*)(hb), c);
      c = mfma16(a1, *(const bf16x8*)(hb + 32), c);
      c = mfma16(a2, *(const bf16x8*)(hb + 64), c);
      c = mfma16(a3, *(const bf16x8*)(hb + 96), c);
      float* sp = S + (m0 + quad * 4) * 130 + 16 * n + r16;
      sp[0] = c[0]; sp[130] = c[1]; sp[260] = c[2]; sp[390] = c[3];
    }
  }
  __syncthreads();
  {
    float* outb = out + (size_t)b * 16384;
#pragma unroll
    for (int i = 0; i < 32; i++) {
      float hv = S[(obase + i) * 130 + l] + fc_b[obase + i];
      outb[(obase + i) * 128 + l] = fmaxf(hv, 0.f) + res[i];
    }
  }
}

extern "C" void kernel_launch(void* const* d_in, const int* in_sizes, int n_in,
                              void* d_out, int out_size, void* d_ws, size_t ws_size,
                              hipStream_t stream) {
  const float* x       = (const float*)d_in[0];
  const int*   mask    = (const int*)d_in[1];
  const float* dw_w    = (const float*)d_in[2];
  const float* dw_b    = (const float*)d_in[3];
  const float* pw_w    = (const float*)d_in[4];
  const float* pw_b    = (const float*)d_in[5];
  const float* normb_w = (const float*)d_in[6];
  const float* normb_b = (const float*)d_in[7];
  const float* norms_w = (const float*)d_in[8];
  const float* norms_b = (const float*)d_in[9];
  const float* norme_w = (const float*)d_in[10];
  const float* norme_b = (const float*)d_in[11];
  const float* Wq      = (const float*)d_in[12];
  const float* bq      = (const float*)d_in[13];
  const float* Wk      = (const float*)d_in[14];
  const float* bk      = (const float*)d_in[15];
  const float* Wv      = (const float*)d_in[16];
  const float* bv      = (const float*)d_in[17];
  const float* Wo      = (const float*)d_in[18];
  const float* bo      = (const float*)d_in[19];
  const float* fc_w    = (const float*)d_in[20];
  const float* fc_b    = (const float*)d_in[21];
  float* out = (float*)d_out;
  unsigned short* wsu = (unsigned short*)d_ws;
  const float* pe = (const float*)(wsu + WSU_END);
  int B = in_sizes[0] / 16384;

  prep_kernel<<<dim3(10, 128), dim3(128), 0, stream>>>(pw_w, fc_w, Wo, Wq, Wk, Wv, wsu);
  enc_kernel<<<dim3(B), dim3(512), 0, stream>>>(
      x, mask, dw_w, dw_b, pw_b, normb_w, normb_b, norms_w, norms_b,
      norme_w, norme_b, bq, bk, bv, bo, fc_b, wsu, pe, out);
}